// Round 20
// baseline (71.456 us; speedup 1.0000x reference)
//
#include <hip/hip_runtime.h>

// BatchWiseTripletLoss: n=8192, d=128, 512 classes, scalar output.
// Round-20 = round-19 (triangular symmetric sweep, fragment-order ebB,
// LDS-staged B, atomicMax maxima, 6 launches) minus the candidate-push
// machinery:
//  - A row has a hard negative (s > thrNeg) iff maxNeg[row] > thrNeg[row]
//    (thrNeg >= 0.5; maxNegEnc already tracks the max) -> the per-stripe
//    __any vote + atomic append was redundant. Sweep epilogue is leaner
//    and the whole pipeline is now deterministic by construction.
//  - k_fix: parallel flag-scan (expected 0 flagged rows at ~5.7 sigma);
//    for each flagged row, cooperative exact f32 recompute of its negative
//    sims from ebB (fixed col partition + LDS tree = deterministic).
// Sweep sync/MFMA structure untouched (r18's ILP experiment regressed;
// r15-r18 established the ~40us wall is structure-insensitive).
// launch_bounds(512,2): 256-reg budget (the 128-reg cap of (256,4)/(512,4)
// spilled catastrophically in rounds 3/6/11).

#define D 128
#define NCLS 512
#define FCAP 256               // flagged-row capacity (expected ~0 used)
#define PSIM_CAP (512 * 1024)  // sum m^2 ~ 139K expected; 2MB safety
#define MARGIN 0.1f
#define NEG_FLOOR 0.6f
#define NINF -1e30f

typedef short bf16x8 __attribute__((ext_vector_type(8)));
typedef float f32x4 __attribute__((ext_vector_type(4)));

__device__ __forceinline__ unsigned short f2bf(float f) {
  unsigned u = __float_as_uint(f);
  u += 0x7FFFu + ((u >> 16) & 1u);
  return (unsigned short)(u >> 16);
}

// Order-monotonic float<->uint encoding (for atomicMax).
__device__ __forceinline__ unsigned fenc(float f) {
  unsigned u = __float_as_uint(f);
  return (u & 0x80000000u) ? ~u : (u | 0x80000000u);
}
__device__ __forceinline__ float fdec(unsigned e) {
  unsigned u = (e & 0x80000000u) ? (e & 0x7FFFFFFFu) : ~e;
  return __uint_as_float(u);
}

// ---- S1: per-chunk histogram + stable in-chunk rank; zero aux state ----
__global__ void k_histrank(const int* __restrict__ tgt, int* __restrict__ H,
                           int* __restrict__ rnk,
                           unsigned* __restrict__ maxNegEnc) {
  __shared__ int cls[128];
  __shared__ int h[NCLS];
  const int chunk = blockIdx.x;  // 64 chunks x 128 rows
  const int tid = threadIdx.x;   // 128 threads
  const int i = chunk * 128 + tid;
  cls[tid] = tgt[i];
  for (int k = tid; k < NCLS; k += 128) h[k] = 0;
  __syncthreads();
  const int c = cls[tid];
  atomicAdd(&h[c], 1);
  int r = 0;
  for (int j = 0; j < tid; ++j) r += (cls[j] == c);  // stable in-chunk rank
  rnk[i] = r;
  maxNegEnc[i] = 0u;  // encoded -inf floor (re-init every launch)
  __syncthreads();
  for (int k = tid; k < NCLS; k += 128) H[chunk * NCLS + k] = h[k];
}

// ---- S2: scans -> per-chunk scatter bases, class starts, psim bases ----
__global__ void k_scan(const int* __restrict__ H, int* __restrict__ CB,
                       int* __restrict__ cls_start, int* __restrict__ pbase,
                       int n) {
  __shared__ int wsum[8], wsum2[8];
  const int c = threadIdx.x;  // class, 512 threads
  int t = 0;
#pragma unroll 8
  for (int k = 0; k < 64; ++k) t += H[k * NCLS + c];
  const int t2 = t * t;
  const int lane = c & 63, w = c >> 6;
  int v = t, v2 = t2;
#pragma unroll
  for (int off = 1; off < 64; off <<= 1) {
    int u = __shfl_up(v, off, 64);
    int u2 = __shfl_up(v2, off, 64);
    if (lane >= off) {
      v += u;
      v2 += u2;
    }
  }
  if (lane == 63) {
    wsum[w] = v;
    wsum2[w] = v2;
  }
  __syncthreads();
  if (c < 8) {
    int x = wsum[c], x2 = wsum2[c];
#pragma unroll
    for (int off = 1; off < 8; off <<= 1) {
      int u = __shfl_up(x, off, 64);
      int u2 = __shfl_up(x2, off, 64);
      if (lane >= off) {
        x += u;
        x2 += u2;
      }
    }
    wsum[c] = x;
    wsum2[c] = x2;
  }
  __syncthreads();
  int base = v + ((w > 0) ? wsum[w - 1] : 0) - t;      // excl prefix of m
  int base2 = v2 + ((w > 0) ? wsum2[w - 1] : 0) - t2;  // excl prefix of m^2
  cls_start[c] = base;
  if (c == NCLS - 1) cls_start[NCLS] = n;
  pbase[c] = base2;
  int run = base;
#pragma unroll 8
  for (int k = 0; k < 64; ++k) {
    CB[k * NCLS + c] = run;
    run += H[k * NCLS + c];
  }
}

// ---- K1: normalize ORIGINAL rows, scatter-write to sorted positions ----
__global__ void k_normS(const float* __restrict__ emb,
                        const int* __restrict__ tgt,
                        const int* __restrict__ rnk, const int* __restrict__ CB,
                        const int* __restrict__ cls_start,
                        const int* __restrict__ pbase, uint4* __restrict__ ebB,
                        int* __restrict__ tgtS, int* __restrict__ rowS0,
                        int* __restrict__ rowM, int* __restrict__ rowBase,
                        int n) {
  const int s = blockIdx.x;          // original 16-row stripe
  const int rl = threadIdx.x >> 4;   // row within stripe
  const int c16 = threadIdx.x & 15;  // 16B chunk within row
  const int orig = s * 16 + rl;
  const float* q = emb + (size_t)orig * D + c16 * 8;
  float4 v0 = *(const float4*)q;
  float4 v1 = *(const float4*)(q + 4);
  float ss = v0.x * v0.x + v0.y * v0.y + v0.z * v0.z + v0.w * v0.w +
             v1.x * v1.x + v1.y * v1.y + v1.z * v1.z + v1.w * v1.w;
#pragma unroll
  for (int off = 1; off < 16; off <<= 1) ss += __shfl_xor(ss, off, 64);
  float invn = 1.0f / fmaxf(sqrtf(ss), 1e-12f);
  uint4 wv;
  wv.x = (unsigned)f2bf(v0.x * invn) | ((unsigned)f2bf(v0.y * invn) << 16);
  wv.y = (unsigned)f2bf(v0.z * invn) | ((unsigned)f2bf(v0.w * invn) << 16);
  wv.z = (unsigned)f2bf(v1.x * invn) | ((unsigned)f2bf(v1.y * invn) << 16);
  wv.w = (unsigned)f2bf(v1.z * invn) | ((unsigned)f2bf(v1.w * invn) << 16);
  const int cls = tgt[orig];
  const int chunk = orig >> 7;
  const int pos = CB[chunk * NCLS + cls] + rnk[orig];  // sorted row index
  const int sstripe = pos >> 4, srl = pos & 15;
  const int ks = c16 >> 2, g = c16 & 3;
  ebB[((sstripe * 4 + ks) * 64) + (g * 16 + srl)] = wv;
  if (c16 == 0) {
    int s0 = cls_start[cls];
    tgtS[pos] = cls;
    rowS0[pos] = s0;
    rowM[pos] = cls_start[cls + 1] - s0;
    rowBase[pos] = pbase[cls];
  }
}

// ---- K2: symmetric sweep, 8 waves x 32 rows, compact unroll-1 loop ----
__global__ __launch_bounds__(512, 2) void k_passN(
    const bf16x8* __restrict__ ebB, const int* __restrict__ tgtS,
    const int* __restrict__ rowS0, const int* __restrict__ rowM,
    const int* __restrict__ rowBase, float* __restrict__ psim,
    unsigned* __restrict__ maxNegEnc, int n) {
  __shared__ char Bs[32768];          // 8 stripes x 4 KB, fragment order
  __shared__ float colbuf[8][8][16];  // [stripe][wave][l15] col-max
  __shared__ int sBuf[16];            // slo/shi per stripe

  const int tid = threadIdx.x;
  const int lane = tid & 63;
  const int w = tid >> 6;  // 0..7
  const int l15 = lane & 15, g = lane >> 4;

  // Triangular decode: tiles (bi, bj) with bj >= 2*bi.
  const int nby = n >> 7;  // 64 col slices
  int t = blockIdx.x, bi = 0, rem = nby;
  while (t >= rem) {
    t -= rem;
    ++bi;
    rem -= 2;
  }
  const int bj = 2 * bi + t;
  const bool colside = (bj >= 2 * bi + 2);  // strictly above: double duty
  const int cs0 = bj * 8;
  const int rbase = bi * 256 + w * 32;  // this wave's 32-row panel

  {  // stage B slice: contiguous 32 KB linear copy (512 threads x 4 iters)
    const char* src = (const char*)ebB + (size_t)cs0 * 4096;
#pragma unroll
    for (int i = 0; i < 4; ++i) {
      __builtin_amdgcn_global_load_lds(
          (const __attribute__((address_space(1))) void*)(src + i * 8192 +
                                                          tid * 16),
          (__attribute__((address_space(3))) void*)(Bs + i * 8192 + tid * 16),
          16, 0, 0);
    }
  }
  if (tid < 16) {  // stripe class ranges into LDS
    int si = tid >> 1, which = tid & 1;
    sBuf[tid] = tgtS[(cs0 + si) * 16 + which * 15];
  }

  const int sA = rbase >> 4;
  const int clo = tgtS[rbase], chi = tgtS[rbase + 31];

  bf16x8 a[2][4];
#pragma unroll
  for (int mt = 0; mt < 2; ++mt)
#pragma unroll
    for (int ks = 0; ks < 4; ++ks)
      a[mt][ks] = ebB[((sA + mt) * 4 + ks) * 64 + lane];

  float accN[2][4];
#pragma unroll
  for (int mt = 0; mt < 2; ++mt)
#pragma unroll
    for (int r = 0; r < 4; ++r) accN[mt][r] = NINF;

  __syncthreads();  // B + sBuf resident

#pragma unroll 1
  for (int si = 0; si < 8; ++si) {
    const int cs = cs0 + si;
    bf16x8 b[4];
#pragma unroll
    for (int ks = 0; ks < 4; ++ks)
      b[ks] = *(const bf16x8*)(Bs + si * 4096 + ks * 1024 + lane * 16);
    const int slo = sBuf[2 * si], shi = sBuf[2 * si + 1];

    f32x4 acc[2];
#pragma unroll
    for (int mt = 0; mt < 2; ++mt) acc[mt] = (f32x4){0.f, 0.f, 0.f, 0.f};
    __builtin_amdgcn_s_setprio(1);
#pragma unroll
    for (int ks = 0; ks < 4; ++ks)
#pragma unroll
      for (int mt = 0; mt < 2; ++mt)
        acc[mt] = __builtin_amdgcn_mfma_f32_16x16x32_bf16(a[mt][ks], b[ks],
                                                          acc[mt], 0, 0, 0);
    __builtin_amdgcn_s_setprio(0);

    const bool dirty = (clo <= shi) && (slo <= chi);
    float colMax = NINF;  // per-lane max over this lane's 8 (neg) elements
    if (!dirty) {         // pure negatives: 8 fmax (+ tree only if colside)
#pragma unroll
      for (int mt = 0; mt < 2; ++mt)
#pragma unroll
        for (int r = 0; r < 4; ++r)
          accN[mt][r] = fmaxf(accN[mt][r], acc[mt][r]);
      if (colside) {
        float m0x =
            fmaxf(fmaxf(acc[0][0], acc[0][1]), fmaxf(acc[0][2], acc[0][3]));
        float m1x =
            fmaxf(fmaxf(acc[1][0], acc[1][1]), fmaxf(acc[1][2], acc[1][3]));
        colMax = fmaxf(m0x, m1x);
      }
    } else {  // class-range overlap (rare): psim stores + neg tracking
      const int tc = tgtS[cs * 16 + l15];
      const int col = cs * 16 + l15;
      int4 ta = *(const int4*)(tgtS + rbase + g * 4);
      int4 tb = *(const int4*)(tgtS + rbase + 16 + g * 4);
      int tr[2][4] = {{ta.x, ta.y, ta.z, ta.w}, {tb.x, tb.y, tb.z, tb.w}};
#pragma unroll
      for (int mt = 0; mt < 2; ++mt)
#pragma unroll
        for (int r = 0; r < 4; ++r) {
          float s = acc[mt][r];
          const int row = rbase + mt * 16 + g * 4 + r;
          if (tr[mt][r] == tc) {  // same class: store sim (both sides)
            int s0 = rowS0[row];  // col shares s0/m/base (same class)
            int m = rowM[row];
            int b0 = rowBase[row];
            psim[b0 + (row - s0) * m + (col - s0)] = s;
            if (colside) psim[b0 + (col - s0) * m + (row - s0)] = s;
          } else {
            accN[mt][r] = fmaxf(accN[mt][r], s);
            colMax = fmaxf(colMax, s);
          }
        }
    }
    if (colside) {  // reduce colMax over the 4 g-groups; g==0 writes LDS
      float v = fmaxf(colMax, __shfl_xor(colMax, 16, 64));
      v = fmaxf(v, __shfl_xor(v, 32, 64));
      if (lane < 16) colbuf[si][w][l15] = v;
    }
  }

  // Row-side: reduce accN over the 16 l15-lanes, deterministic atomicMax.
#pragma unroll
  for (int mt = 0; mt < 2; ++mt)
#pragma unroll
    for (int r = 0; r < 4; ++r) {
      float vn = accN[mt][r];
#pragma unroll
      for (int off = 1; off < 16; off <<= 1)
        vn = fmaxf(vn, __shfl_xor(vn, off, 64));
      if (l15 == 0)
        atomicMax(&maxNegEnc[rbase + mt * 16 + g * 4 + r], fenc(vn));
    }

  // Col-side: combine the 8 waves' col-maxes, one atomicMax per column.
  if (colside) {
    __syncthreads();
    if (tid < 128) {
      int si = tid >> 4, l = tid & 15;
      float v = colbuf[si][0][l];
#pragma unroll
      for (int k = 1; k < 8; ++k) v = fmaxf(v, colbuf[si][k][l]);
      atomicMax(&maxNegEnc[(cs0 + si) * 16 + l], fenc(v));
    }
  }
}

// ---- K3: fused per-row stats + block partial sum ----
__global__ void k_stats(const float* __restrict__ psim,
                        const int* __restrict__ rowS0,
                        const int* __restrict__ rowM,
                        const int* __restrict__ rowBase,
                        const unsigned* __restrict__ maxNegEnc,
                        float* __restrict__ thrNeg, float* __restrict__ bpart,
                        int n) {
  __shared__ float red[256];
  int p = blockIdx.x * 256 + threadIdx.x;
  float contrib = 0.f;
  int m = rowM[p];
  if (m <= 1) {
    thrNeg[p] = 1e30f;  // no positive: row contributes 0; never flagged
  } else {
    float tp = fdec(maxNegEnc[p]) + MARGIN;  // thr_pos
    int i = p - rowS0[p];
    const float* row = psim + rowBase[p] + (size_t)i * m;
    float mp = NINF, pl = 0.f;
    for (int j = 0; j < m; ++j) {
      if (j == i) continue;  // self
      float s = row[j];
      mp = fmaxf(mp, s);
      pl += (s < tp) ? (1.f - s) : 0.f;
    }
    thrNeg[p] = fmaxf(NEG_FLOOR, mp) - MARGIN;
    contrib = pl;
  }
  red[threadIdx.x] = contrib;
  __syncthreads();
  for (int off = 128; off > 0; off >>= 1) {
    if ((int)threadIdx.x < off) red[threadIdx.x] += red[threadIdx.x + off];
    __syncthreads();
  }
  if (threadIdx.x == 0) bpart[blockIdx.x] = red[0];
}

// ---- K4: flag-scan + rare exact recompute + final scalar ----
// A row needs a negative-loss contribution iff maxNeg[row] > thrNeg[row]
// (expected ~0 rows: thrNeg >= 0.5 is ~5.7 sigma for cosine sims).
// For each flagged row: cooperative f32 recompute of all its negative
// sims from ebB (fixed col partition + LDS tree => deterministic).
__global__ void k_fix(const uint4* __restrict__ ebB,
                      const int* __restrict__ tgtS,
                      const int* __restrict__ rowM,
                      const unsigned* __restrict__ maxNegEnc,
                      const float* __restrict__ thrNeg,
                      const float* __restrict__ bpart, float* __restrict__ out,
                      int n, int nb) {
  __shared__ int list[FCAP];
  __shared__ unsigned lcnt;
  __shared__ float rowbuf[128];
  __shared__ float red[256];
  __shared__ float totS;
  const int tid = threadIdx.x;  // 256 threads
  if (tid == 0) lcnt = 0u;
  __syncthreads();
  // Parallel flag scan: thread t covers rows [t*32, t*32+32).
  for (int k = 0; k < 32; ++k) {
    int p = tid * 32 + k;
    if (rowM[p] > 1 && fdec(maxNegEnc[p]) > thrNeg[p]) {
      unsigned idx = atomicAdd(&lcnt, 1u);
      if (idx < FCAP) list[idx] = p;
    }
  }
  __syncthreads();
  int k = (int)min(lcnt, (unsigned)FCAP);
  if (tid == 0) {  // sort tiny list; sum block partials in fixed order
    for (int i = 0; i < k; ++i)
      for (int j = i + 1; j < k; ++j)
        if (list[j] < list[i]) {
          int tmp = list[i];
          list[i] = list[j];
          list[j] = tmp;
        }
    float tot = 0.f;
    for (int i = 0; i < nb; ++i) tot += bpart[i];
    totS = tot;
  }
  __syncthreads();
  for (int ii = 0; ii < k; ++ii) {
    const int p = list[ii];
    if (tid < 16) {  // load row p (bf16 fragments) into f32 rowbuf
      int stripe = p >> 4, rl = p & 15, ks = tid >> 2, g = tid & 3;
      uint4 v = ebB[(stripe * 4 + ks) * 64 + (g * 16 + rl)];
      unsigned uu[4] = {v.x, v.y, v.z, v.w};
#pragma unroll
      for (int e = 0; e < 4; ++e) {
        rowbuf[tid * 8 + e * 2] = __uint_as_float(uu[e] << 16);
        rowbuf[tid * 8 + e * 2 + 1] = __uint_as_float(uu[e] & 0xFFFF0000u);
      }
    }
    __syncthreads();
    const int myCls = tgtS[p];
    const float thr = thrNeg[p];
    float acc = 0.f;
    for (int c = tid * 32; c < tid * 32 + 32; ++c) {  // fixed partition
      if (tgtS[c] == myCls) continue;  // same class (incl self) excluded
      int stripe = c >> 4, rl = c & 15;
      float s = 0.f;
#pragma unroll
      for (int c16 = 0; c16 < 16; ++c16) {
        int ks = c16 >> 2, g = c16 & 3;
        uint4 v = ebB[(stripe * 4 + ks) * 64 + (g * 16 + rl)];
        unsigned uu[4] = {v.x, v.y, v.z, v.w};
#pragma unroll
        for (int e = 0; e < 4; ++e) {
          float b0 = __uint_as_float(uu[e] << 16);
          float b1 = __uint_as_float(uu[e] & 0xFFFF0000u);
          s += rowbuf[c16 * 8 + e * 2] * b0 + rowbuf[c16 * 8 + e * 2 + 1] * b1;
        }
      }
      acc += (s > thr) ? s : 0.f;
    }
    red[tid] = acc;
    __syncthreads();
    for (int off = 128; off > 0; off >>= 1) {
      if (tid < off) red[tid] += red[tid + off];
      __syncthreads();
    }
    if (tid == 0) totS += red[0];
    __syncthreads();
  }
  if (tid == 0) out[0] = totS / (float)n;
}

extern "C" void kernel_launch(void* const* d_in, const int* in_sizes, int n_in,
                              void* d_out, int out_size, void* d_ws,
                              size_t ws_size, hipStream_t stream) {
  const float* emb = (const float*)d_in[0];
  const int* tgt = (const int*)d_in[1];
  float* out = (float*)d_out;
  const int n = in_sizes[1];  // 8192

  char* ws = (char*)d_ws;
  uint4* ebB = (uint4*)ws;                         // 2 MB
  float* psim = (float*)(ws + (size_t)n * D * 2);  // 2 MB
  float* thrNeg = psim + PSIM_CAP;                 // [n]
  float* bpart = thrNeg + n;                       // [32] (pad 64)
  unsigned* maxNegEnc = (unsigned*)(bpart + 64);   // [n]
  int* cls_start = (int*)(maxNegEnc + n);          // [513] (pad 1024)
  int* pbase = cls_start + 1024;                   // [512] (pad 1024)
  int* H = pbase + 1024;                           // [64][512]
  int* CB = H + 64 * NCLS;                         // [64][512]
  int* rnk = CB + 64 * NCLS;                       // [n]
  int* tgtS = rnk + n;                             // [n]
  int* rowS0 = tgtS + n;                           // [n]
  int* rowM = rowS0 + n;                           // [n]
  int* rowBase = rowM + n;                         // [n]

  k_histrank<<<n / 128, 128, 0, stream>>>(tgt, H, rnk, maxNegEnc);
  k_scan<<<1, NCLS, 0, stream>>>(H, CB, cls_start, pbase, n);
  k_normS<<<n / 16, 256, 0, stream>>>(emb, tgt, rnk, CB, cls_start, pbase,
                                      ebB, tgtS, rowS0, rowM, rowBase, n);

  const int nbx = n / 256, nby = n / 128;
  const int tblocks = nbx * nby - nbx * (nbx - 1);  // 1056 for n=8192
  k_passN<<<tblocks, 512, 0, stream>>>((const bf16x8*)ebB, tgtS, rowS0, rowM,
                                       rowBase, psim, maxNegEnc, n);
  k_stats<<<n / 256, 256, 0, stream>>>(psim, rowS0, rowM, rowBase, maxNegEnc,
                                       thrNeg, bpart, n);
  k_fix<<<1, 256, 0, stream>>>(ebB, tgtS, rowM, maxNegEnc, thrNeg, bpart, out,
                               n, n / 256);
}

// Round 21
// 61.253 us; speedup vs baseline: 1.1666x; 1.1666x over previous
//
#include <hip/hip_runtime.h>

// BatchWiseTripletLoss: n=8192, d=128, 512 classes, scalar output.
// Round-21 = round-20 with the flag-scan moved OUT of the single-block
// k_fix (r20's regression: one block serially walking 8192 rows of
// rowM/maxNegEnc/thrNeg = ~10us of unhidden L2 latency) and INTO k_stats,
// which already holds maxNeg and thrNeg in registers across 32 parallel
// blocks. Flagged rows (expected 0 at ~5.7 sigma; thrNeg >= 0.5) are
// atomically appended; k_fix sorts the tiny list first, so the float
// summation order is fixed -> deterministic regardless of append order.
// Sweep (k_passN) and prep identical to r19/r20 verified structure.
// launch_bounds(512,2): 256-reg budget (the 128-reg cap of (256,4)/(512,4)
// spilled catastrophically in rounds 3/6/11).

#define D 128
#define NCLS 512
#define FCAP 256               // flagged-row capacity (expected ~0 used)
#define PSIM_CAP (512 * 1024)  // sum m^2 ~ 139K expected; 2MB safety
#define MARGIN 0.1f
#define NEG_FLOOR 0.6f
#define NINF -1e30f

typedef short bf16x8 __attribute__((ext_vector_type(8)));
typedef float f32x4 __attribute__((ext_vector_type(4)));

__device__ __forceinline__ unsigned short f2bf(float f) {
  unsigned u = __float_as_uint(f);
  u += 0x7FFFu + ((u >> 16) & 1u);
  return (unsigned short)(u >> 16);
}

// Order-monotonic float<->uint encoding (for atomicMax).
__device__ __forceinline__ unsigned fenc(float f) {
  unsigned u = __float_as_uint(f);
  return (u & 0x80000000u) ? ~u : (u | 0x80000000u);
}
__device__ __forceinline__ float fdec(unsigned e) {
  unsigned u = (e & 0x80000000u) ? (e & 0x7FFFFFFFu) : ~e;
  return __uint_as_float(u);
}

// ---- S1: per-chunk histogram + stable in-chunk rank; zero aux state ----
__global__ void k_histrank(const int* __restrict__ tgt, int* __restrict__ H,
                           int* __restrict__ rnk,
                           unsigned* __restrict__ maxNegEnc,
                           unsigned* __restrict__ fcnt) {
  __shared__ int cls[128];
  __shared__ int h[NCLS];
  const int chunk = blockIdx.x;  // 64 chunks x 128 rows
  const int tid = threadIdx.x;   // 128 threads
  const int i = chunk * 128 + tid;
  if (chunk == 0 && tid == 0) *fcnt = 0u;
  cls[tid] = tgt[i];
  for (int k = tid; k < NCLS; k += 128) h[k] = 0;
  __syncthreads();
  const int c = cls[tid];
  atomicAdd(&h[c], 1);
  int r = 0;
  for (int j = 0; j < tid; ++j) r += (cls[j] == c);  // stable in-chunk rank
  rnk[i] = r;
  maxNegEnc[i] = 0u;  // encoded -inf floor (re-init every launch)
  __syncthreads();
  for (int k = tid; k < NCLS; k += 128) H[chunk * NCLS + k] = h[k];
}

// ---- S2: scans -> per-chunk scatter bases, class starts, psim bases ----
__global__ void k_scan(const int* __restrict__ H, int* __restrict__ CB,
                       int* __restrict__ cls_start, int* __restrict__ pbase,
                       int n) {
  __shared__ int wsum[8], wsum2[8];
  const int c = threadIdx.x;  // class, 512 threads
  int t = 0;
#pragma unroll 8
  for (int k = 0; k < 64; ++k) t += H[k * NCLS + c];
  const int t2 = t * t;
  const int lane = c & 63, w = c >> 6;
  int v = t, v2 = t2;
#pragma unroll
  for (int off = 1; off < 64; off <<= 1) {
    int u = __shfl_up(v, off, 64);
    int u2 = __shfl_up(v2, off, 64);
    if (lane >= off) {
      v += u;
      v2 += u2;
    }
  }
  if (lane == 63) {
    wsum[w] = v;
    wsum2[w] = v2;
  }
  __syncthreads();
  if (c < 8) {
    int x = wsum[c], x2 = wsum2[c];
#pragma unroll
    for (int off = 1; off < 8; off <<= 1) {
      int u = __shfl_up(x, off, 64);
      int u2 = __shfl_up(x2, off, 64);
      if (lane >= off) {
        x += u;
        x2 += u2;
      }
    }
    wsum[c] = x;
    wsum2[c] = x2;
  }
  __syncthreads();
  int base = v + ((w > 0) ? wsum[w - 1] : 0) - t;      // excl prefix of m
  int base2 = v2 + ((w > 0) ? wsum2[w - 1] : 0) - t2;  // excl prefix of m^2
  cls_start[c] = base;
  if (c == NCLS - 1) cls_start[NCLS] = n;
  pbase[c] = base2;
  int run = base;
#pragma unroll 8
  for (int k = 0; k < 64; ++k) {
    CB[k * NCLS + c] = run;
    run += H[k * NCLS + c];
  }
}

// ---- K1: normalize ORIGINAL rows, scatter-write to sorted positions ----
__global__ void k_normS(const float* __restrict__ emb,
                        const int* __restrict__ tgt,
                        const int* __restrict__ rnk, const int* __restrict__ CB,
                        const int* __restrict__ cls_start,
                        const int* __restrict__ pbase, uint4* __restrict__ ebB,
                        int* __restrict__ tgtS, int* __restrict__ rowS0,
                        int* __restrict__ rowM, int* __restrict__ rowBase,
                        int n) {
  const int s = blockIdx.x;          // original 16-row stripe
  const int rl = threadIdx.x >> 4;   // row within stripe
  const int c16 = threadIdx.x & 15;  // 16B chunk within row
  const int orig = s * 16 + rl;
  const float* q = emb + (size_t)orig * D + c16 * 8;
  float4 v0 = *(const float4*)q;
  float4 v1 = *(const float4*)(q + 4);
  float ss = v0.x * v0.x + v0.y * v0.y + v0.z * v0.z + v0.w * v0.w +
             v1.x * v1.x + v1.y * v1.y + v1.z * v1.z + v1.w * v1.w;
#pragma unroll
  for (int off = 1; off < 16; off <<= 1) ss += __shfl_xor(ss, off, 64);
  float invn = 1.0f / fmaxf(sqrtf(ss), 1e-12f);
  uint4 wv;
  wv.x = (unsigned)f2bf(v0.x * invn) | ((unsigned)f2bf(v0.y * invn) << 16);
  wv.y = (unsigned)f2bf(v0.z * invn) | ((unsigned)f2bf(v0.w * invn) << 16);
  wv.z = (unsigned)f2bf(v1.x * invn) | ((unsigned)f2bf(v1.y * invn) << 16);
  wv.w = (unsigned)f2bf(v1.z * invn) | ((unsigned)f2bf(v1.w * invn) << 16);
  const int cls = tgt[orig];
  const int chunk = orig >> 7;
  const int pos = CB[chunk * NCLS + cls] + rnk[orig];  // sorted row index
  const int sstripe = pos >> 4, srl = pos & 15;
  const int ks = c16 >> 2, g = c16 & 3;
  ebB[((sstripe * 4 + ks) * 64) + (g * 16 + srl)] = wv;
  if (c16 == 0) {
    int s0 = cls_start[cls];
    tgtS[pos] = cls;
    rowS0[pos] = s0;
    rowM[pos] = cls_start[cls + 1] - s0;
    rowBase[pos] = pbase[cls];
  }
}

// ---- K2: symmetric sweep, 8 waves x 32 rows, compact unroll-1 loop ----
__global__ __launch_bounds__(512, 2) void k_passN(
    const bf16x8* __restrict__ ebB, const int* __restrict__ tgtS,
    const int* __restrict__ rowS0, const int* __restrict__ rowM,
    const int* __restrict__ rowBase, float* __restrict__ psim,
    unsigned* __restrict__ maxNegEnc, int n) {
  __shared__ char Bs[32768];          // 8 stripes x 4 KB, fragment order
  __shared__ float colbuf[8][8][16];  // [stripe][wave][l15] col-max
  __shared__ int sBuf[16];            // slo/shi per stripe

  const int tid = threadIdx.x;
  const int lane = tid & 63;
  const int w = tid >> 6;  // 0..7
  const int l15 = lane & 15, g = lane >> 4;

  // Triangular decode: tiles (bi, bj) with bj >= 2*bi.
  const int nby = n >> 7;  // 64 col slices
  int t = blockIdx.x, bi = 0, rem = nby;
  while (t >= rem) {
    t -= rem;
    ++bi;
    rem -= 2;
  }
  const int bj = 2 * bi + t;
  const bool colside = (bj >= 2 * bi + 2);  // strictly above: double duty
  const int cs0 = bj * 8;
  const int rbase = bi * 256 + w * 32;  // this wave's 32-row panel

  {  // stage B slice: contiguous 32 KB linear copy (512 threads x 4 iters)
    const char* src = (const char*)ebB + (size_t)cs0 * 4096;
#pragma unroll
    for (int i = 0; i < 4; ++i) {
      __builtin_amdgcn_global_load_lds(
          (const __attribute__((address_space(1))) void*)(src + i * 8192 +
                                                          tid * 16),
          (__attribute__((address_space(3))) void*)(Bs + i * 8192 + tid * 16),
          16, 0, 0);
    }
  }
  if (tid < 16) {  // stripe class ranges into LDS
    int si = tid >> 1, which = tid & 1;
    sBuf[tid] = tgtS[(cs0 + si) * 16 + which * 15];
  }

  const int sA = rbase >> 4;
  const int clo = tgtS[rbase], chi = tgtS[rbase + 31];

  bf16x8 a[2][4];
#pragma unroll
  for (int mt = 0; mt < 2; ++mt)
#pragma unroll
    for (int ks = 0; ks < 4; ++ks)
      a[mt][ks] = ebB[((sA + mt) * 4 + ks) * 64 + lane];

  float accN[2][4];
#pragma unroll
  for (int mt = 0; mt < 2; ++mt)
#pragma unroll
    for (int r = 0; r < 4; ++r) accN[mt][r] = NINF;

  __syncthreads();  // B + sBuf resident

#pragma unroll 1
  for (int si = 0; si < 8; ++si) {
    const int cs = cs0 + si;
    bf16x8 b[4];
#pragma unroll
    for (int ks = 0; ks < 4; ++ks)
      b[ks] = *(const bf16x8*)(Bs + si * 4096 + ks * 1024 + lane * 16);
    const int slo = sBuf[2 * si], shi = sBuf[2 * si + 1];

    f32x4 acc[2];
#pragma unroll
    for (int mt = 0; mt < 2; ++mt) acc[mt] = (f32x4){0.f, 0.f, 0.f, 0.f};
    __builtin_amdgcn_s_setprio(1);
#pragma unroll
    for (int ks = 0; ks < 4; ++ks)
#pragma unroll
      for (int mt = 0; mt < 2; ++mt)
        acc[mt] = __builtin_amdgcn_mfma_f32_16x16x32_bf16(a[mt][ks], b[ks],
                                                          acc[mt], 0, 0, 0);
    __builtin_amdgcn_s_setprio(0);

    const bool dirty = (clo <= shi) && (slo <= chi);
    float colMax = NINF;  // per-lane max over this lane's 8 (neg) elements
    if (!dirty) {         // pure negatives: 8 fmax (+ tree only if colside)
#pragma unroll
      for (int mt = 0; mt < 2; ++mt)
#pragma unroll
        for (int r = 0; r < 4; ++r)
          accN[mt][r] = fmaxf(accN[mt][r], acc[mt][r]);
      if (colside) {
        float m0x =
            fmaxf(fmaxf(acc[0][0], acc[0][1]), fmaxf(acc[0][2], acc[0][3]));
        float m1x =
            fmaxf(fmaxf(acc[1][0], acc[1][1]), fmaxf(acc[1][2], acc[1][3]));
        colMax = fmaxf(m0x, m1x);
      }
    } else {  // class-range overlap (rare): psim stores + neg tracking
      const int tc = tgtS[cs * 16 + l15];
      const int col = cs * 16 + l15;
      int4 ta = *(const int4*)(tgtS + rbase + g * 4);
      int4 tb = *(const int4*)(tgtS + rbase + 16 + g * 4);
      int tr[2][4] = {{ta.x, ta.y, ta.z, ta.w}, {tb.x, tb.y, tb.z, tb.w}};
#pragma unroll
      for (int mt = 0; mt < 2; ++mt)
#pragma unroll
        for (int r = 0; r < 4; ++r) {
          float s = acc[mt][r];
          const int row = rbase + mt * 16 + g * 4 + r;
          if (tr[mt][r] == tc) {  // same class: store sim (both sides)
            int s0 = rowS0[row];  // col shares s0/m/base (same class)
            int m = rowM[row];
            int b0 = rowBase[row];
            psim[b0 + (row - s0) * m + (col - s0)] = s;
            if (colside) psim[b0 + (col - s0) * m + (row - s0)] = s;
          } else {
            accN[mt][r] = fmaxf(accN[mt][r], s);
            colMax = fmaxf(colMax, s);
          }
        }
    }
    if (colside) {  // reduce colMax over the 4 g-groups; g==0 writes LDS
      float v = fmaxf(colMax, __shfl_xor(colMax, 16, 64));
      v = fmaxf(v, __shfl_xor(v, 32, 64));
      if (lane < 16) colbuf[si][w][l15] = v;
    }
  }

  // Row-side: reduce accN over the 16 l15-lanes, deterministic atomicMax.
#pragma unroll
  for (int mt = 0; mt < 2; ++mt)
#pragma unroll
    for (int r = 0; r < 4; ++r) {
      float vn = accN[mt][r];
#pragma unroll
      for (int off = 1; off < 16; off <<= 1)
        vn = fmaxf(vn, __shfl_xor(vn, off, 64));
      if (l15 == 0)
        atomicMax(&maxNegEnc[rbase + mt * 16 + g * 4 + r], fenc(vn));
    }

  // Col-side: combine the 8 waves' col-maxes, one atomicMax per column.
  if (colside) {
    __syncthreads();
    if (tid < 128) {
      int si = tid >> 4, l = tid & 15;
      float v = colbuf[si][0][l];
#pragma unroll
      for (int k = 1; k < 8; ++k) v = fmaxf(v, colbuf[si][k][l]);
      atomicMax(&maxNegEnc[(cs0 + si) * 16 + l], fenc(v));
    }
  }
}

// ---- K3: fused per-row stats + block partial sum + hard-neg flagging ----
__global__ void k_stats(const float* __restrict__ psim,
                        const int* __restrict__ rowS0,
                        const int* __restrict__ rowM,
                        const int* __restrict__ rowBase,
                        const unsigned* __restrict__ maxNegEnc,
                        float* __restrict__ thrNeg, float* __restrict__ bpart,
                        int* __restrict__ flist, unsigned* __restrict__ fcnt,
                        int n) {
  __shared__ float red[256];
  int p = blockIdx.x * 256 + threadIdx.x;
  float contrib = 0.f;
  int m = rowM[p];
  if (m <= 1) {
    thrNeg[p] = 1e30f;  // no positive: row contributes 0; never flagged
  } else {
    float mn = fdec(maxNegEnc[p]);  // max_neg for this row
    float tp = mn + MARGIN;         // thr_pos
    int i = p - rowS0[p];
    const float* row = psim + rowBase[p] + (size_t)i * m;
    float mp = NINF, pl = 0.f;
    for (int j = 0; j < m; ++j) {
      if (j == i) continue;  // self
      float s = row[j];
      mp = fmaxf(mp, s);
      pl += (s < tp) ? (1.f - s) : 0.f;
    }
    float tn = fmaxf(NEG_FLOOR, mp) - MARGIN;
    thrNeg[p] = tn;
    contrib = pl;
    if (mn > tn) {  // hard negative exists (~never at 5.7 sigma)
      unsigned idx = atomicAdd(fcnt, 1u);
      if (idx < FCAP) flist[idx] = p;
    }
  }
  red[threadIdx.x] = contrib;
  __syncthreads();
  for (int off = 128; off > 0; off >>= 1) {
    if ((int)threadIdx.x < off) red[threadIdx.x] += red[threadIdx.x + off];
    __syncthreads();
  }
  if (threadIdx.x == 0) bpart[blockIdx.x] = red[0];
}

// ---- K4: tiny fixup (sorted flagged list -> exact f32 recompute) ----
__global__ void k_fix(const uint4* __restrict__ ebB,
                      const int* __restrict__ tgtS,
                      const unsigned* __restrict__ fcnt,
                      const int* __restrict__ flist,
                      const float* __restrict__ thrNeg,
                      const float* __restrict__ bpart, float* __restrict__ out,
                      int n, int nb) {
  __shared__ int list[FCAP];
  __shared__ float rowbuf[128];
  __shared__ float red[256];
  __shared__ float totS;
  const int tid = threadIdx.x;  // 256 threads
  int k = (int)min(*fcnt, (unsigned)FCAP);
  for (int i = tid; i < k; i += 256) list[i] = flist[i];
  __syncthreads();
  if (tid == 0) {  // sort tiny list -> deterministic summation order
    for (int i = 0; i < k; ++i)
      for (int j = i + 1; j < k; ++j)
        if (list[j] < list[i]) {
          int tmp = list[i];
          list[i] = list[j];
          list[j] = tmp;
        }
    float tot = 0.f;
    for (int i = 0; i < nb; ++i) tot += bpart[i];
    totS = tot;
  }
  __syncthreads();
  for (int ii = 0; ii < k; ++ii) {
    const int p = list[ii];
    if (tid < 16) {  // load row p (bf16 fragments) into f32 rowbuf
      int stripe = p >> 4, rl = p & 15, ks = tid >> 2, g = tid & 3;
      uint4 v = ebB[(stripe * 4 + ks) * 64 + (g * 16 + rl)];
      unsigned uu[4] = {v.x, v.y, v.z, v.w};
#pragma unroll
      for (int e = 0; e < 4; ++e) {
        rowbuf[tid * 8 + e * 2] = __uint_as_float(uu[e] << 16);
        rowbuf[tid * 8 + e * 2 + 1] = __uint_as_float(uu[e] & 0xFFFF0000u);
      }
    }
    __syncthreads();
    const int myCls = tgtS[p];
    const float thr = thrNeg[p];
    float acc = 0.f;
    for (int c = tid * 32; c < tid * 32 + 32; ++c) {  // fixed partition
      if (tgtS[c] == myCls) continue;  // same class (incl self) excluded
      int stripe = c >> 4, rl = c & 15;
      float s = 0.f;
#pragma unroll
      for (int c16 = 0; c16 < 16; ++c16) {
        int ks = c16 >> 2, g = c16 & 3;
        uint4 v = ebB[(stripe * 4 + ks) * 64 + (g * 16 + rl)];
        unsigned uu[4] = {v.x, v.y, v.z, v.w};
#pragma unroll
        for (int e = 0; e < 4; ++e) {
          float b0 = __uint_as_float(uu[e] << 16);
          float b1 = __uint_as_float(uu[e] & 0xFFFF0000u);
          s += rowbuf[c16 * 8 + e * 2] * b0 + rowbuf[c16 * 8 + e * 2 + 1] * b1;
        }
      }
      acc += (s > thr) ? s : 0.f;
    }
    red[tid] = acc;
    __syncthreads();
    for (int off = 128; off > 0; off >>= 1) {
      if (tid < off) red[tid] += red[tid + off];
      __syncthreads();
    }
    if (tid == 0) totS += red[0];
    __syncthreads();
  }
  if (tid == 0) out[0] = totS / (float)n;
}

extern "C" void kernel_launch(void* const* d_in, const int* in_sizes, int n_in,
                              void* d_out, int out_size, void* d_ws,
                              size_t ws_size, hipStream_t stream) {
  const float* emb = (const float*)d_in[0];
  const int* tgt = (const int*)d_in[1];
  float* out = (float*)d_out;
  const int n = in_sizes[1];  // 8192

  char* ws = (char*)d_ws;
  uint4* ebB = (uint4*)ws;                         // 2 MB
  float* psim = (float*)(ws + (size_t)n * D * 2);  // 2 MB
  float* thrNeg = psim + PSIM_CAP;                 // [n]
  float* bpart = thrNeg + n;                       // [32] (pad 64)
  unsigned* maxNegEnc = (unsigned*)(bpart + 64);   // [n]
  unsigned* fcnt = maxNegEnc + n;                  // [1] (pad 64)
  int* flist = (int*)(fcnt + 64);                  // [FCAP]
  int* cls_start = flist + FCAP;                   // [513] (pad 1024)
  int* pbase = cls_start + 1024;                   // [512] (pad 1024)
  int* H = pbase + 1024;                           // [64][512]
  int* CB = H + 64 * NCLS;                         // [64][512]
  int* rnk = CB + 64 * NCLS;                       // [n]
  int* tgtS = rnk + n;                             // [n]
  int* rowS0 = tgtS + n;                           // [n]
  int* rowM = rowS0 + n;                           // [n]
  int* rowBase = rowM + n;                         // [n]

  k_histrank<<<n / 128, 128, 0, stream>>>(tgt, H, rnk, maxNegEnc, fcnt);
  k_scan<<<1, NCLS, 0, stream>>>(H, CB, cls_start, pbase, n);
  k_normS<<<n / 16, 256, 0, stream>>>(emb, tgt, rnk, CB, cls_start, pbase,
                                      ebB, tgtS, rowS0, rowM, rowBase, n);

  const int nbx = n / 256, nby = n / 128;
  const int tblocks = nbx * nby - nbx * (nbx - 1);  // 1056 for n=8192
  k_passN<<<tblocks, 512, 0, stream>>>((const bf16x8*)ebB, tgtS, rowS0, rowM,
                                       rowBase, psim, maxNegEnc, n);
  k_stats<<<n / 256, 256, 0, stream>>>(psim, rowS0, rowM, rowBase, maxNegEnc,
                                       thrNeg, bpart, flist, fcnt, n);
  k_fix<<<1, 256, 0, stream>>>(ebB, tgtS, fcnt, flist, thrNeg, bpart, out, n,
                               n / 256);
}